// Round 6
// baseline (392.537 us; speedup 1.0000x reference)
//
#include <hip/hip_runtime.h>
#include <hip/hip_bf16.h>

#define N_TOK 131072
#define DIM   512
#define HID   512
#define NEXP  10

using bf16x8 = __attribute__((ext_vector_type(8))) short;
using f32x4  = __attribute__((ext_vector_type(4))) float;

__device__ __forceinline__ short f2bf(float f) {
    union { float f; unsigned u; } v; v.f = f;
    unsigned u = v.u;
    return (short)((u + 0x7FFFu + ((u >> 16) & 1u)) >> 16);   // RNE
}

#define GLOAD16(g, l) __builtin_amdgcn_global_load_lds( \
    (const __attribute__((address_space(1))) void*)(g),  \
    (__attribute__((address_space(3))) void*)(l), 16, 0, 0)

// ---------------- router: logits = x @ Wr^T + br, argmax; also emits xb = bf16(x) ----------------
__global__ __launch_bounds__(256) void router_kernel(
    const float* __restrict__ x, const float* __restrict__ Wr,
    const float* __restrict__ br, int* __restrict__ eid,
    float* __restrict__ ids_out, int* __restrict__ counts,
    short* __restrict__ xb)
{
    __shared__ float wr[NEXP][DIM];
    __shared__ int lcnt[NEXP];
    int tid = threadIdx.x;
    for (int i = tid; i < NEXP * DIM / 4; i += 256)
        ((float4*)wr)[i] = ((const float4*)Wr)[i];
    if (tid < NEXP) lcnt[tid] = 0;
    __syncthreads();

    int lane  = tid & 63;
    int wave  = tid >> 6;
    int gwave = blockIdx.x * 4 + wave;
    int nwav  = gridDim.x * 4;

    for (int t = gwave; t < N_TOK; t += nwav) {
        const float4* xr = (const float4*)(x + (size_t)t * DIM);
        float4 v0 = xr[lane * 2], v1 = xr[lane * 2 + 1];
        float xf[8] = {v0.x, v0.y, v0.z, v0.w, v1.x, v1.y, v1.z, v1.w};
        bf16x8 p;
        #pragma unroll
        for (int j = 0; j < 8; ++j) p[j] = f2bf(xf[j]);
        *(bf16x8*)(xb + (size_t)t * DIM + lane * 8) = p;

        float dot[NEXP];
        #pragma unroll
        for (int e = 0; e < NEXP; ++e) {
            const float* wv = &wr[e][lane * 8];
            float s = 0.f;
            #pragma unroll
            for (int j = 0; j < 8; ++j) s = fmaf(xf[j], wv[j], s);
            dot[e] = s;
        }
        #pragma unroll
        for (int off = 32; off > 0; off >>= 1) {
            #pragma unroll
            for (int e = 0; e < NEXP; ++e) dot[e] += __shfl_xor(dot[e], off, 64);
        }
        if (lane == 0) {
            int best = 0; float bv = dot[0] + br[0];
            #pragma unroll
            for (int e = 1; e < NEXP; ++e) {
                float v = dot[e] + br[e];
                if (v > bv) { bv = v; best = e; }
            }
            eid[t] = best;
            ids_out[t] = (float)best;
            atomicAdd(&lcnt[best], 1);
        }
    }
    __syncthreads();
    if (tid < NEXP) atomicAdd(&counts[tid], lcnt[tid]);
}

// ---------------- prefix sums: token offsets + tile offsets (256-row tiles) ----------------
__global__ void offsets_kernel(const int* __restrict__ counts,
                               int* __restrict__ offsets, int* __restrict__ toff)
{
    if (threadIdx.x == 0) {
        int acc = 0, ta = 0;
        for (int e = 0; e < NEXP; ++e) {
            offsets[e] = acc; toff[e] = ta;
            acc += counts[e]; ta += (counts[e] + 255) >> 8;
        }
        offsets[NEXP] = acc; toff[NEXP] = ta;
    }
}

// ---------------- bucket scatter: perm[offset[e] + pos] = token ----------------
__global__ __launch_bounds__(256) void scatter_kernel(
    const int* __restrict__ eid, const int* __restrict__ offsets,
    int* __restrict__ cursors, int* __restrict__ perm)
{
    __shared__ int lcnt[NEXP], lbase[NEXP];
    int tid = threadIdx.x;
    if (tid < NEXP) lcnt[tid] = 0;
    __syncthreads();
    int t = blockIdx.x * 256 + tid;
    int e = 0, lpos = 0;
    if (t < N_TOK) {
        e = eid[t];
        lpos = atomicAdd(&lcnt[e], 1);
    }
    __syncthreads();
    if (tid < NEXP) lbase[tid] = atomicAdd(&cursors[tid], lcnt[tid]);
    __syncthreads();
    if (t < N_TOK) perm[offsets[e] + lbase[e] + lpos] = t;
}

// ---- transpose-convert weights: [512 k][512 n] f32 -> k-blocked bf16 [16][512 n][32 k] ----
__global__ __launch_bounds__(256) void wconvert_kernel(
    const float* __restrict__ W1, const float* __restrict__ W2,
    short* __restrict__ W1b, short* __restrict__ W2b)
{
    int mat = blockIdx.z;
    const float* src = (mat < NEXP) ? W1 + (size_t)mat * 512 * 512
                                    : W2 + (size_t)(mat - NEXP) * 512 * 512;
    short* dst = (mat < NEXP) ? W1b + (size_t)mat * 512 * 512
                              : W2b + (size_t)(mat - NEXP) * 512 * 512;
    __shared__ float tile[64][65];
    int r0 = blockIdx.y * 64, c0 = blockIdx.x * 64;   // r0 = k base, c0 = n base
    int tid = threadIdx.x;
    int tr = tid >> 4, tc4 = (tid & 15) * 4;
    #pragma unroll
    for (int i = 0; i < 4; ++i) {
        float4 v = *(const float4*)(src + (size_t)(r0 + i * 16 + tr) * 512 + c0 + tc4);
        tile[i * 16 + tr][tc4 + 0] = v.x; tile[i * 16 + tr][tc4 + 1] = v.y;
        tile[i * 16 + tr][tc4 + 2] = v.z; tile[i * 16 + tr][tc4 + 3] = v.w;
    }
    __syncthreads();
    int s   = (r0 + tc4) >> 5;     // 32k-block
    int kin = (r0 + tc4) & 31;
    #pragma unroll
    for (int i = 0; i < 4; ++i) {
        int cc = i * 16 + tr;      // n within tile
        ushort4 o;
        o.x = (ushort)f2bf(tile[tc4 + 0][cc]); o.y = (ushort)f2bf(tile[tc4 + 1][cc]);
        o.z = (ushort)f2bf(tile[tc4 + 2][cc]); o.w = (ushort)f2bf(tile[tc4 + 3][cc]);
        *(ushort4*)(dst + (size_t)s * 16384 + (size_t)(c0 + cc) * 32 + kin) = o;
    }
}

// ---------------- MFMA expert GEMM: 256 x 256 tile, K=512, 8 waves, 4-phase K-tiles ----------------
// 2 LDS buffers (128 KB). Per K-tile (BK=64): 4 phases (kh x rh), 16 MFMA each.
// Chunk c of tile i+1 staged at phase c of tile i (4 phases ahead); vmcnt(4) counted waits.
// Chunks: c0 = B kh0, c1 = A kh0, c2 = B kh1, c3 = A kh1 (16 KB each, 2 gloads/thread).
// LDS slot swizzle: 16B slot qphys = qlog ^ (row&3), applied source-side + read-side.
template<int LAYER>
__global__ __launch_bounds__(512, 2) void expert_gemm(
    const short* __restrict__ xb, const short* __restrict__ hA,
    const short* __restrict__ WT, const float* __restrict__ bias,
    const int* __restrict__ offsets, const int* __restrict__ toff,
    const int* __restrict__ perm,
    short* __restrict__ hOut, float* __restrict__ out)
{
    int g = blockIdx.x;
    if (g >= toff[NEXP]) return;
    int e = 0;
    #pragma unroll
    for (int k = 1; k < NEXP; ++k) e += (g >= toff[k]);
    int beg = offsets[e], cnt = offsets[e + 1] - beg;
    int m0 = (g - toff[e]) * 256;
    int nb = blockIdx.y * 256;

    __shared__ int toks[256];
    __shared__ short lds_s[65536];     // 128 KB: [buf2][A/B][kh2][row256][32k]

    int tid = threadIdx.x, lane = tid & 63, w = tid >> 6;
    if (tid < 256) toks[tid] = perm[beg + min(m0 + tid, cnt - 1)];
    __syncthreads();

    char* LDS = (char*)lds_s;
    const short* WTe = WT + (size_t)e * 512 * 512;

    // ---- staging precompute: 2 gload instructions per thread per chunk ----
    const short* aBase[2];
    const short* bBase[2];
    int ldsOff[2];
    #pragma unroll
    for (int k = 0; k < 2; ++k) {
        int s   = w * 128 + k * 64 + lane;   // 16B slot index within 16KB chunk
        int row = s >> 2;
        int ql  = (s & 3) ^ (row & 3);       // logical k-quarter held at this slot
        bBase[k] = WTe + (size_t)(nb + row) * 32 + ql * 8;   // + (ti*2+kh)*16384
        if (LAYER == 1) aBase[k] = xb + (size_t)toks[row] * DIM + ql * 8;   // + ti*64+kh*32
        else            aBase[k] = hA + (size_t)(beg + min(m0 + row, cnt - 1)) * HID + ql * 8;
        ldsOff[k] = w * 2048 + k * 1024;
    }

    // chunk c of tile ti -> buffer b
    auto stage_chunk = [&](int ti, int c, int b) {
        int kh  = c >> 1;
        if (c & 1) {   // A chunk
            char* dst = LDS + b * 65536 + kh * 16384;
            GLOAD16(aBase[0] + ti * 64 + kh * 32, dst + ldsOff[0]);
            GLOAD16(aBase[1] + ti * 64 + kh * 32, dst + ldsOff[1]);
        } else {       // B chunk
            char* dst = LDS + b * 65536 + 32768 + kh * 16384;
            GLOAD16(bBase[0] + (ti * 2 + kh) * 16384, dst + ldsOff[0]);
            GLOAD16(bBase[1] + (ti * 2 + kh) * 16384, dst + ldsOff[1]);
        }
    };

    // ---- fragment read offsets (swizzled) ----
    int wr = w >> 2, wc = w & 3, lrow = lane & 15;
    int qp = (lane >> 4) ^ (lane & 3);                       // row&3 == lane&3 for all frag rows
    int offA0 = (wr * 128 + lrow) * 64 + qp * 16;            // + i8*1024 + kh*16384 + buf*65536
    int offB0 = 32768 + (wc * 64 + lrow) * 64 + qp * 16;     // + cf*1024 + kh*16384 + buf*65536

    f32x4 acc[8][4];
    #pragma unroll
    for (int i = 0; i < 8; ++i)
        #pragma unroll
        for (int j = 0; j < 4; ++j) acc[i][j] = (f32x4){0.f, 0.f, 0.f, 0.f};

    // ---- prologue: stage all 4 chunks of tile 0 into buf 0 (8 loads/thread) ----
    stage_chunk(0, 0, 0); stage_chunk(0, 1, 0);
    stage_chunk(0, 2, 0); stage_chunk(0, 3, 0);

    bf16x8 bv[4];

    // ---- main loop: 8 K-tiles x 4 phases ----
    #pragma unroll
    for (int i = 0; i < 8; ++i) {
        int b = i & 1;
        char* cbuf = LDS + b * 65536;
        #pragma unroll
        for (int p = 0; p < 4; ++p) {
            int kh = p >> 1, rh = p & 1;
            // counted waits at k-half boundaries (ledger: see header comment)
            if (p == 0) {
                asm volatile("s_waitcnt vmcnt(4)" ::: "memory");
            } else if (p == 2) {
                if (i == 7) asm volatile("s_waitcnt vmcnt(0)" ::: "memory");
                else        asm volatile("s_waitcnt vmcnt(4)" ::: "memory");
            }
            __builtin_amdgcn_s_barrier();
            __builtin_amdgcn_sched_barrier(0);

            // ds_read fragments for this phase
            if (rh == 0) {
                #pragma unroll
                for (int cf = 0; cf < 4; ++cf)
                    bv[cf] = *(const bf16x8*)(cbuf + offB0 + cf * 1024 + kh * 16384);
            }
            bf16x8 af[4];
            #pragma unroll
            for (int r = 0; r < 4; ++r) {
                int i8 = rh * 4 + r;
                af[r] = *(const bf16x8*)(cbuf + offA0 + i8 * 1024 + kh * 16384);
            }

            // prefetch: chunk p of next K-tile into the other buffer
            if (i < 7) stage_chunk(i + 1, p, b ^ 1);

            __builtin_amdgcn_s_setprio(1);
            #pragma unroll
            for (int r = 0; r < 4; ++r)
                #pragma unroll
                for (int cf = 0; cf < 4; ++cf)
                    acc[rh * 4 + r][cf] =
                        __builtin_amdgcn_mfma_f32_16x16x32_bf16(af[r], bv[cf], acc[rh * 4 + r][cf], 0, 0, 0);
            __builtin_amdgcn_s_setprio(0);
        }
    }

    // ---- epilogue ----
    const float* be = bias + (size_t)e * 512;
    int colb = nb + wc * 64 + lrow;
    float bvv[4];
    #pragma unroll
    for (int j = 0; j < 4; ++j) bvv[j] = be[colb + j * 16];

    #pragma unroll
    for (int i = 0; i < 8; ++i) {
        #pragma unroll
        for (int q = 0; q < 4; ++q) {
            int rr = wr * 128 + i * 16 + ((lane >> 4) << 2) + q;
            if (m0 + rr < cnt) {
                if (LAYER == 1) {
                    short* hp = hOut + (size_t)(beg + m0 + rr) * HID + colb;
                    #pragma unroll
                    for (int j = 0; j < 4; ++j) {
                        float v = acc[i][j][q] + bvv[j];
                        hp[j * 16] = f2bf(v > 0.f ? v : 0.f);
                    }
                } else {
                    float* op = out + (size_t)toks[rr] * HID + colb;
                    #pragma unroll
                    for (int j = 0; j < 4; ++j)
                        op[j * 16] = acc[i][j][q] + bvv[j];
                }
            }
        }
    }
}

extern "C" void kernel_launch(void* const* d_in, const int* in_sizes, int n_in,
                              void* d_out, int out_size, void* d_ws, size_t ws_size,
                              hipStream_t stream)
{
    const float* x  = (const float*)d_in[0];
    const float* Wr = (const float*)d_in[1];
    const float* br = (const float*)d_in[2];
    const float* W1 = (const float*)d_in[3];
    const float* b1 = (const float*)d_in[4];
    const float* W2 = (const float*)d_in[5];
    const float* b2 = (const float*)d_in[6];

    float* out     = (float*)d_out;
    float* ids_out = out + (size_t)N_TOK * HID;

    char* ws     = (char*)d_ws;
    int* counts  = (int*)ws;            // 16 ints
    int* offsets = counts + 16;         // 11 used
    int* toff    = counts + 32;         // 11 used
    int* cursors = counts + 48;         // 16
    int* eid     = (int*)(ws + 1024);
    int* perm    = eid + N_TOK;
    short* W1b   = (short*)(ws + 1024 + (size_t)2 * N_TOK * 4);
    short* W2b   = W1b + (size_t)NEXP * 512 * 512;
    short* h     = W2b + (size_t)NEXP * 512 * 512;
    short* xb    = h   + (size_t)N_TOK * HID;

    hipMemsetAsync(d_ws, 0, 1024, stream);
    router_kernel<<<2048, 256, 0, stream>>>(x, Wr, br, eid, ids_out, counts, xb);
    wconvert_kernel<<<dim3(8, 8, 2 * NEXP), 256, 0, stream>>>(W1, W2, W1b, W2b);
    offsets_kernel<<<1, 64, 0, stream>>>(counts, offsets, toff);
    scatter_kernel<<<512, 256, 0, stream>>>(eid, offsets, cursors, perm);

    int ntiles = (N_TOK + 255) / 256 + NEXP;   // upper bound on 256-row tiles
    expert_gemm<1><<<dim3(ntiles, 2), 512, 0, stream>>>(xb, nullptr, W1b, b1, offsets, toff, perm, h, nullptr);
    expert_gemm<2><<<dim3(ntiles, 2), 512, 0, stream>>>(nullptr, h, W2b, b2, offsets, toff, perm, nullptr, out);
}